// Round 1
// baseline (1144.434 us; speedup 1.0000x reference)
//
#include <hip/hip_runtime.h>
#include <math.h>

#define BM 128
#define BN 128
#define BK 16
#define EPSV 1e-12f
#define NEG_INF_V -1000000000.0f
#define NBINS 2048
#define MAXC 1024

// ---------------- normalize x rows (one wave per row) ----------------
__global__ void xnorm_kernel(const float* __restrict__ x, float* __restrict__ xn, int D) {
    int row = blockIdx.x;
    int lane = threadIdx.x;          // 64 lanes
    const float4* xr = (const float4*)(x + (size_t)row * D);
    float4* xo = (float4*)(xn + (size_t)row * D);
    int per = (D / 4) / 64;          // D=512 -> 2
    float ss = 0.f;
    float4 v[4];
    for (int i = 0; i < per; ++i) {
        float4 t = xr[lane * per + i];
        v[i] = t;
        ss += t.x * t.x + t.y * t.y + t.z * t.z + t.w * t.w;
    }
    for (int off = 32; off >= 1; off >>= 1) ss += __shfl_xor(ss, off);
    float denom = fmaxf(sqrtf(ss), EPSV);
    for (int i = 0; i < per; ++i) {
        float4 t = v[i];
        t.x /= denom; t.y /= denom; t.z /= denom; t.w /= denom;
        xo[lane * per + i] = t;
    }
}

// ---------------- key inverse norms (one wave per key row) ----------------
__global__ void kinv_kernel(const float* __restrict__ keys, float* __restrict__ kinv,
                            int M, int D) {
    int wave = threadIdx.x >> 6;
    int lane = threadIdx.x & 63;
    int row = blockIdx.x * 4 + wave;
    if (row >= M) return;
    const float4* kr = (const float4*)(keys + (size_t)row * D);
    int per = (D / 4) / 64;          // 2
    float ss = 0.f;
    for (int i = 0; i < per; ++i) {
        float4 t = kr[lane * per + i];
        ss += t.x * t.x + t.y * t.y + t.z * t.z + t.w * t.w;
    }
    for (int off = 32; off >= 1; off >>= 1) ss += __shfl_xor(ss, off);
    if (lane == 0) kinv[row] = 1.0f / fmaxf(sqrtf(ss), EPSV);
}

// ---------------- fp32 SGEMM: scores[b,m] = xn[b,:] . (keys[m,:] * kinv[m]) ----------------
__global__ __launch_bounds__(256, 2)
void gemm_kernel(const float* __restrict__ xn, const float* __restrict__ keys,
                 const float* __restrict__ kinv, const int* __restrict__ values,
                 float* __restrict__ scores, int M, int D) {
    __shared__ float As[BK][BM];
    __shared__ float Bs[BK][BN];

    const int tid = threadIdx.x;
    const int row0 = blockIdx.x * BM;     // x-row tile (fast dim -> key-tile L2 reuse)
    const int col0 = blockIdx.y * BN;     // key tile

    // staging: each thread owns one tile-row (lr), half of K (lh)
    const int lr = tid >> 1;              // 0..127
    const int lh = (tid & 1) * 8;         // 0 or 8
    const int arow = row0 + lr;
    const int bcol = col0 + lr;
    const bool bvalid = (bcol < M);
    const float binv = bvalid ? kinv[bcol] : 0.f;

    const int tx = tid & 15;              // col group (8 cols)
    const int ty = tid >> 4;              // row group (8 rows)

    float acc[8][8];
#pragma unroll
    for (int i = 0; i < 8; ++i)
#pragma unroll
        for (int j = 0; j < 8; ++j) acc[i][j] = 0.f;

    for (int k0 = 0; k0 < D; k0 += BK) {
        float4 a0 = *(const float4*)(xn + (size_t)arow * D + k0 + lh);
        float4 a1 = *(const float4*)(xn + (size_t)arow * D + k0 + lh + 4);
        float4 b0 = make_float4(0.f, 0.f, 0.f, 0.f);
        float4 b1 = make_float4(0.f, 0.f, 0.f, 0.f);
        if (bvalid) {
            b0 = *(const float4*)(keys + (size_t)bcol * D + k0 + lh);
            b1 = *(const float4*)(keys + (size_t)bcol * D + k0 + lh + 4);
        }
        __syncthreads();   // WAR guard vs previous iteration's reads
        As[lh + 0][lr] = a0.x; As[lh + 1][lr] = a0.y; As[lh + 2][lr] = a0.z; As[lh + 3][lr] = a0.w;
        As[lh + 4][lr] = a1.x; As[lh + 5][lr] = a1.y; As[lh + 6][lr] = a1.z; As[lh + 7][lr] = a1.w;
        Bs[lh + 0][lr] = b0.x * binv; Bs[lh + 1][lr] = b0.y * binv;
        Bs[lh + 2][lr] = b0.z * binv; Bs[lh + 3][lr] = b0.w * binv;
        Bs[lh + 4][lr] = b1.x * binv; Bs[lh + 5][lr] = b1.y * binv;
        Bs[lh + 6][lr] = b1.z * binv; Bs[lh + 7][lr] = b1.w * binv;
        __syncthreads();

#pragma unroll
        for (int kk = 0; kk < BK; ++kk) {
            float4 af0 = *(const float4*)&As[kk][ty * 8];
            float4 af1 = *(const float4*)&As[kk][ty * 8 + 4];
            float4 bf0 = *(const float4*)&Bs[kk][tx * 8];
            float4 bf1 = *(const float4*)&Bs[kk][tx * 8 + 4];
            float a_[8] = { af0.x, af0.y, af0.z, af0.w, af1.x, af1.y, af1.z, af1.w };
            float b_[8] = { bf0.x, bf0.y, bf0.z, bf0.w, bf1.x, bf1.y, bf1.z, bf1.w };
#pragma unroll
            for (int i = 0; i < 8; ++i)
#pragma unroll
                for (int j = 0; j < 8; ++j)
                    acc[i][j] += a_[i] * b_[j];
        }
    }

    // epilogue: apply empty-key mask, store
    const int cbase = col0 + tx * 8;
    if (cbase + 7 < M) {
        bool msk[8];
#pragma unroll
        for (int j = 0; j < 8; ++j) msk[j] = (values[cbase + j] == -1);
#pragma unroll
        for (int i = 0; i < 8; ++i) {
            int r = row0 + ty * 8 + i;
            float o[8];
#pragma unroll
            for (int j = 0; j < 8; ++j) o[j] = msk[j] ? NEG_INF_V : acc[i][j];
            *(float4*)(scores + (size_t)r * M + cbase) = make_float4(o[0], o[1], o[2], o[3]);
            *(float4*)(scores + (size_t)r * M + cbase + 4) = make_float4(o[4], o[5], o[6], o[7]);
        }
    } else {
#pragma unroll
        for (int j = 0; j < 8; ++j) {
            int c = cbase + j;
            if (c < M) {
                bool mk = (values[c] == -1);
#pragma unroll
                for (int i = 0; i < 8; ++i) {
                    int r = row0 + ty * 8 + i;
                    scores[(size_t)r * M + c] = mk ? NEG_INF_V : acc[i][j];
                }
            }
        }
    }
}

// ---------------- exact top-k per row via histogram threshold + rank ----------------
__device__ __forceinline__ int score_bin(float s) {
    float t = fminf(fmaxf((s + 1.0f) * 1024.0f, 0.0f), 2047.0f);
    return (int)t;
}

__global__ __launch_bounds__(256)
void select_kernel(const float* __restrict__ scores, const int* __restrict__ values,
                   const int* __restrict__ kptr, float* __restrict__ out,
                   int M, int C) {
    const int row = blockIdx.x;
    const int tid = threadIdx.x;
    const int K = *kptr;

    __shared__ int hist[NBINS];
    __shared__ float cs[MAXC];
    __shared__ int ci[MAXC];
    __shared__ int cnt;
    __shared__ int tbin;
    __shared__ float acc[32];

    for (int i = tid; i < NBINS; i += 256) hist[i] = 0;
    if (tid == 0) cnt = 0;
    if (tid < 32) acc[tid] = 0.f;
    __syncthreads();

    const float* srow = scores + (size_t)row * M;
    for (int m = tid; m < M; m += 256) {
        atomicAdd(&hist[score_bin(srow[m])], 1);
    }
    __syncthreads();

    // wave 0: suffix-scan over 64 chunks of 32 bins to locate the k-th-largest bin
    if (tid < 64) {
        const int lane = tid;
        int csum = 0;
#pragma unroll
        for (int j = 0; j < NBINS / 64; ++j) csum += hist[lane * (NBINS / 64) + j];
        int sfx = csum;
#pragma unroll
        for (int off = 1; off < 64; off <<= 1) {
            int o = __shfl_down(sfx, off);
            if (lane + off < 64) sfx += o;
        }
        unsigned long long mask = __ballot(sfx >= K);
        int L = 63 - __builtin_clzll(mask);   // largest chunk whose suffix-count >= K
        int above = (L == 63) ? 0 : __shfl(sfx, L + 1);
        if (lane == L) {
            int c = above;
            int t = L * (NBINS / 64);
            for (int j = NBINS / 64 - 1; j >= 0; --j) {
                c += hist[L * (NBINS / 64) + j];
                if (c >= K) { t = L * (NBINS / 64) + j; break; }
            }
            tbin = t;
        }
    }
    __syncthreads();

    const int T = tbin;
    for (int m = tid; m < M; m += 256) {
        float s = srow[m];
        if (score_bin(s) >= T) {
            int p = atomicAdd(&cnt, 1);
            if (p < MAXC) { cs[p] = s; ci[p] = m; }
        }
    }
    __syncthreads();

    int n = cnt < MAXC ? cnt : MAXC;
    for (int i = tid; i < n; i += 256) {
        float s = cs[i];
        int idx = ci[i];
        int rank = 0;
        for (int j = 0; j < n; ++j) {
            float sj = cs[j];
            rank += (sj > s) || (sj == s && ci[j] < idx);   // lax.top_k tie order
        }
        if (rank < K) {
            int lbl = values[idx];
            if (lbl >= 0) atomicAdd(&acc[lbl], s);
        }
    }
    __syncthreads();
    if (tid < C) out[(size_t)row * C + tid] = acc[tid];
}

extern "C" void kernel_launch(void* const* d_in, const int* in_sizes, int n_in,
                              void* d_out, int out_size, void* d_ws, size_t ws_size,
                              hipStream_t stream) {
    const float* x = (const float*)d_in[0];
    const float* keys = (const float*)d_in[1];
    const int* values = (const int*)d_in[2];
    const int* kptr = (const int*)d_in[3];
    float* out = (float*)d_out;

    const int M = in_sizes[2];            // 60000
    const int D = in_sizes[1] / M;        // 512
    const int B = in_sizes[0] / D;        // 1024
    const int C = out_size / B;           // 10

    float* xn = (float*)d_ws;                               // B*D floats
    float* kinv = xn + (size_t)B * D;                       // M floats
    float* scores = kinv + (size_t)M;                       // B*M floats (16B-aligned for our sizes)

    xnorm_kernel<<<B, 64, 0, stream>>>(x, xn, D);
    kinv_kernel<<<(M + 3) / 4, 256, 0, stream>>>(keys, kinv, M, D);

    dim3 ggrid(B / BM, (M + BN - 1) / BN);                  // row-tiles fastest -> key-tile L2 reuse
    gemm_kernel<<<ggrid, 256, 0, stream>>>(xn, keys, kinv, values, scores, M, D);

    select_kernel<<<B, 256, 0, stream>>>(scores, values, kptr, out, M, C);
}